// Round 9
// baseline (258.079 us; speedup 1.0000x reference)
//
#include <hip/hip_runtime.h>
#include <hip/hip_bf16.h>

typedef _Float16 half8 __attribute__((ext_vector_type(8)));
typedef _Float16 half4 __attribute__((ext_vector_type(4)));
typedef float f32x4 __attribute__((ext_vector_type(4)));

#define KDIM 1024
#define NDIM 1024
#define MROWS 16384   // B*L = 4*4096

#define GLD_LDS16(g, l)                                                  \
  __builtin_amdgcn_global_load_lds(                                      \
      (const __attribute__((address_space(1))) void*)(g),                \
      (__attribute__((address_space(3))) void*)(l), 16, 0, 0)

// ---------------------------------------------------------------------------
// fp32 -> fp16 convert, 32 elems/thread, 8 independent coalesced float4
// loads then 4 half8 stores (high ILP). Grid sized exactly: n = blocks*8192.
// blockIdx.y selects tensor (up to 4 pairs).
// ---------------------------------------------------------------------------
__global__ __launch_bounds__(256)
void cvt32(const float* __restrict__ s0, _Float16* __restrict__ d0,
           const float* __restrict__ s1, _Float16* __restrict__ d1,
           const float* __restrict__ s2, _Float16* __restrict__ d2,
           const float* __restrict__ s3, _Float16* __restrict__ d3) {
  const float* src;
  _Float16* dst;
  switch (blockIdx.y) {
    case 0: src = s0; dst = d0; break;
    case 1: src = s1; dst = d1; break;
    case 2: src = s2; dst = d2; break;
    default: src = s3; dst = d3; break;
  }
  const size_t g = (size_t)blockIdx.x * 8192;
  const int tid = threadIdx.x;
  float4 f[8];
#pragma unroll
  for (int j = 0; j < 8; ++j)
    f[j] = *(const float4*)(src + g + j * 1024 + tid * 4);
#pragma unroll
  for (int j = 0; j < 4; ++j) {
    half8 h;
    h[0] = (_Float16)f[2 * j].x;     h[1] = (_Float16)f[2 * j].y;
    h[2] = (_Float16)f[2 * j].z;     h[3] = (_Float16)f[2 * j].w;
    h[4] = (_Float16)f[2 * j + 1].x; h[5] = (_Float16)f[2 * j + 1].y;
    h[6] = (_Float16)f[2 * j + 1].z; h[7] = (_Float16)f[2 * j + 1].w;
    // store layout must match load layout: halves g+j*2048+tid*8 correspond
    // to floats loaded at j'=2j,2j+1 -> indices g + 2j*1024 + tid*4 (+1024)
    *(half4*)(dst + g + 2 * j * 1024 + tid * 4) = half4{h[0], h[1], h[2], h[3]};
    *(half4*)(dst + g + (2 * j + 1) * 1024 + tid * 4) = half4{h[4], h[5], h[6], h[7]};
  }
}

// ---------------------------------------------------------------------------
// BK32 GEMM (round-8 proven winner): Y = act(X @ W^T + bias), fp16 in,
// fp32 accum. 256x128, BK=32, 8 waves, 3-buf 72KB unified smem ->
// 2 blocks/CU. Counted-vmcnt(3) 2-ahead pipeline, rule-21 swizzle
// (slot ^= row&3 via inverse-swizzled global source).
// ACT: 0 none, 1 elu+1. TRANS: 1 = per-head transposed fp16 (half4).
// FUSE: 1 = linear-attention epilogue: Ct (64KB, overlays smem) re-fragments
// Q as MFMA-A; KVTx B-fragments read DIRECTLY from global (L2-hot);
// Z-scale; store att fp16 natural. Requires ACT=1, TRANS=0, TOUT=_Float16.
// ---------------------------------------------------------------------------
template <int ACT, int TRANS, int FUSE, typename TOUT>
__global__ __launch_bounds__(512, 2)
void gemm_bk32(const _Float16* __restrict__ X, const _Float16* __restrict__ W,
               const float* __restrict__ bias, TOUT* __restrict__ Y,
               const _Float16* __restrict__ KVTx) {
  constexpr int BM = 256, BN = 128, BK = 32;
  __shared__ char smem[73728];                    // 72 KB
  _Float16* As = (_Float16*)smem;                 // 48 KB (3 x 16 KB)
  _Float16* Bs = (_Float16*)(smem + 49152);       // 24 KB (3 x 8 KB)

  const int tid  = threadIdx.x;
  const int lane = tid & 63;
  const int w    = tid >> 6;
  const int wm   = w >> 1;
  const int wn   = w & 1;

  const int bid = blockIdx.x;
  const int wid = (bid & 7) * 64 + (bid >> 3);
  const int m0  = (wid >> 3) * BM;
  const int n0  = (wid & 7) * BN;

  const int lrw = lane >> 2;                     // 0..15
  const int gsl = (lane & 3) ^ (lrw & 3);        // inverse-swizzled slot
  const _Float16* gA = X + (size_t)(m0 + w * 16 + lrw) * KDIM + gsl * 8;
  const _Float16* gB = W + (size_t)(n0 + w * 16 + lrw) * KDIM + gsl * 8;

#define STAGE32(kt, bidx)                                                     \
  {                                                                           \
    const int k0s = (kt) * BK;                                                \
    _Float16* la = As + (bidx) * (BM * BK) + (w * 16) * BK;                   \
    _Float16* lb = Bs + (bidx) * (BN * BK) + (w * 16) * BK;                   \
    GLD_LDS16(gA + k0s, la);                                                  \
    GLD_LDS16(gA + (size_t)128 * KDIM + k0s, la + 128 * BK);                  \
    GLD_LDS16(gB + k0s, lb);                                                  \
  }

  const int rsl = ((lane >> 4) ^ (lane & 3)) << 4;

  f32x4 acc[4][4] = {};

  STAGE32(0, 0);
  STAGE32(1, 1);
  asm volatile("s_waitcnt vmcnt(3)" ::: "memory");
  asm volatile("s_barrier" ::: "memory");

  int bc = 0;
  for (int t = 0; t < 32; ++t) {
    int bs = bc + 2; if (bs >= 3) bs -= 3;
    const char* Ab = (const char*)As + bc * (BM * BK * 2);
    const char* Bb = (const char*)Bs + bc * (BN * BK * 2);

    half8 afr[4], bfr[4];
#pragma unroll
    for (int mi = 0; mi < 4; ++mi) {
      int row = wm * 64 + mi * 16 + (lane & 15);
      afr[mi] = *(const half8*)(Ab + row * 64 + rsl);
    }
#pragma unroll
    for (int ni = 0; ni < 4; ++ni) {
      int row = wn * 64 + ni * 16 + (lane & 15);
      bfr[ni] = *(const half8*)(Bb + row * 64 + rsl);
    }

    if (t < 30) STAGE32(t + 2, bs);

    __builtin_amdgcn_s_setprio(1);
#pragma unroll
    for (int mi = 0; mi < 4; ++mi)
#pragma unroll
      for (int ni = 0; ni < 4; ++ni)
        acc[mi][ni] = __builtin_amdgcn_mfma_f32_16x16x32_f16(
            afr[mi], bfr[ni], acc[mi][ni], 0, 0, 0);
    __builtin_amdgcn_s_setprio(0);

    if (t < 30) {
      asm volatile("s_waitcnt vmcnt(3)" ::: "memory");
      asm volatile("s_barrier" ::: "memory");
    } else if (t == 30) {
      asm volatile("s_waitcnt vmcnt(0)" ::: "memory");
      asm volatile("s_barrier" ::: "memory");
    }
    ++bc; if (bc == 3) bc = 0;
  }
#undef STAGE32

  if constexpr (FUSE) {
    // ---- fused linear-attention epilogue (Ct overlays smem; B from global)
    __syncthreads();
    _Float16* Ct = (_Float16*)smem;   // [256 rows][128 cols], 256B rows
#pragma unroll
    for (int ni = 0; ni < 4; ++ni) {
      int cl   = wn * 64 + ni * 16 + (lane & 15);
      float bv = bias[n0 + cl];
#pragma unroll
      for (int mi = 0; mi < 4; ++mi) {
#pragma unroll
        for (int i = 0; i < 4; ++i) {
          int row = wm * 64 + mi * 16 + ((lane >> 4) << 2) + i;
          float v = acc[mi][ni][i] + bv;
          v = (v > 0.f) ? (v + 1.f) : __expf(v);
          int byte = row * 256 + cl * 2;
          byte ^= (row & 7) << 4;
          *(_Float16*)((char*)Ct + byte) = (_Float16)v;
        }
      }
    }
    __syncthreads();
    // B-fragments straight from KVTx (L2-hot): head = bh0 + wn
    const int bh0 = ((m0 >> 12) << 4) + (n0 >> 6);
    const _Float16* kvp = KVTx + (size_t)(bh0 + wn) * 5120;
    f32x4 acc2[4][5] = {};
#pragma unroll
    for (int kk = 0; kk < 2; ++kk) {
      half8 afr2[4], bfr2[5];
#pragma unroll
      for (int m = 0; m < 4; ++m) {
        int row  = wm * 64 + m * 16 + (lane & 15);
        int byte = row * 256 + wn * 128 + kk * 64 + ((lane >> 4) << 4);
        byte ^= (row & 7) << 4;
        afr2[m] = *(const half8*)((const char*)Ct + byte);
      }
#pragma unroll
      for (int n = 0; n < 5; ++n) {
        int row = n * 16 + (lane & 15);
        bfr2[n] = *(const half8*)(kvp + row * 64 + kk * 32 + ((lane >> 4) << 3));
      }
#pragma unroll
      for (int m = 0; m < 4; ++m)
#pragma unroll
        for (int n = 0; n < 5; ++n)
          acc2[m][n] = __builtin_amdgcn_mfma_f32_16x16x32_f16(
              afr2[m], bfr2[n], acc2[m][n], 0, 0, 0);
    }
#pragma unroll
    for (int m = 0; m < 4; ++m) {
#pragma unroll
      for (int i = 0; i < 4; ++i) {
        float dn = __shfl(acc2[m][4][i], lane & 48);
        float z  = 1.f / (dn + 1e-6f);
        size_t row = (size_t)m0 + wm * 64 + m * 16 + ((lane >> 4) << 2) + i;
#pragma unroll
        for (int n = 0; n < 4; ++n) {
          int col = n0 + wn * 64 + n * 16 + (lane & 15);
          Y[row * NDIM + col] = (TOUT)(acc2[m][n][i] * z);
        }
      }
    }
    return;
  }

#pragma unroll
  for (int ni = 0; ni < 4; ++ni) {
    int col  = n0 + wn * 64 + ni * 16 + (lane & 15);
    float bv = bias[col];
#pragma unroll
    for (int mi = 0; mi < 4; ++mi) {
      int r0 = m0 + wm * 64 + mi * 16 + ((lane >> 4) << 2);
      if constexpr (TRANS) {
        int b  = r0 >> 12;
        int l0 = r0 & 4095;
        half4 hv;
#pragma unroll
        for (int i = 0; i < 4; ++i) {
          float v = acc[mi][ni][i] + bv;
          if constexpr (ACT == 1) v = (v > 0.f) ? (v + 1.f) : __expf(v);
          hv[i] = (_Float16)v;
        }
        *(half4*)((_Float16*)Y + ((size_t)(b * 1024 + col)) * 4096 + l0) = hv;
      } else {
#pragma unroll
        for (int i = 0; i < 4; ++i) {
          float v = acc[mi][ni][i] + bv;
          if constexpr (ACT == 1) v = (v > 0.f) ? (v + 1.f) : __expf(v);
          Y[(size_t)(r0 + i) * NDIM + col] = (TOUT)v;
        }
      }
    }
  }
}

// ---------------------------------------------------------------------------
// kv_mfma: per (bh, chunk of 1024 l): partial C'[e][d] = sum_l VT[e][l]*KT[d][l]
// A = VT rows + synthesized ones-row (m-frag 4 -> Ksum); B = KT rows.
// ---------------------------------------------------------------------------
__global__ __launch_bounds__(256, 2)
void kv_mfma(const _Float16* __restrict__ KT, const _Float16* __restrict__ VT,
             _Float16* __restrict__ pKV) {
  const int bh = blockIdx.x;      // 0..63
  const int ch = blockIdx.y;      // 0..3
  const int tid  = threadIdx.x;
  const int lane = tid & 63;
  const int w    = tid >> 6;

  __shared__ _Float16 As[64 * 64];
  __shared__ _Float16 Bs[64 * 64];

  const int lr = lane >> 3;
  const int ls = (lane & 7) ^ lr;
  const size_t lbase = (size_t)ch * 1024 + ls * 8;
  const _Float16* gA = VT + (size_t)(bh * 64 + w * 16 + lr) * 4096 + lbase;
  const _Float16* gB = KT + (size_t)(bh * 64 + w * 16 + lr) * 4096 + lbase;
  _Float16* ldsA = As + (w * 16) * 64;
  _Float16* ldsB = Bs + (w * 16) * 64;

  half8 aones;
#pragma unroll
  for (int j = 0; j < 8; ++j) aones[j] = (lane & 15) == 0 ? (_Float16)1.0f : (_Float16)0.0f;

  f32x4 acc[5] = {};

  for (int k0 = 0; k0 < 1024; k0 += 64) {
    __syncthreads();
#pragma unroll
    for (int c = 0; c < 2; ++c) {
      GLD_LDS16(gA + k0 + (size_t)(c * 8) * 4096, ldsA + c * 8 * 64);
      GLD_LDS16(gB + k0 + (size_t)(c * 8) * 4096, ldsB + c * 8 * 64);
    }
    __syncthreads();

    half8 afr[4][2], bfr[2];
#pragma unroll
    for (int m = 0; m < 4; ++m)
#pragma unroll
      for (int kk = 0; kk < 2; ++kk) {
        int row  = m * 16 + (lane & 15);
        int byte = row * 128 + ((lane >> 4) << 4) + kk * 64;
        byte ^= (row & 7) << 4;
        afr[m][kk] = *(const half8*)((const char*)As + byte);
      }
#pragma unroll
    for (int kk = 0; kk < 2; ++kk) {
      int row  = w * 16 + (lane & 15);
      int byte = row * 128 + ((lane >> 4) << 4) + kk * 64;
      byte ^= (row & 7) << 4;
      bfr[kk] = *(const half8*)((const char*)Bs + byte);
    }
#pragma unroll
    for (int kk = 0; kk < 2; ++kk) {
#pragma unroll
      for (int m = 0; m < 4; ++m)
        acc[m] = __builtin_amdgcn_mfma_f32_16x16x32_f16(afr[m][kk], bfr[kk],
                                                        acc[m], 0, 0, 0);
      acc[4] = __builtin_amdgcn_mfma_f32_16x16x32_f16(aones, bfr[kk],
                                                      acc[4], 0, 0, 0);
    }
  }

  _Float16* outp = pKV + ((size_t)ch * 64 + bh) * 5120;
  const int col = w * 16 + (lane & 15);
#pragma unroll
  for (int m = 0; m < 5; ++m) {
#pragma unroll
    for (int i = 0; i < 4; ++i) {
      int row = m * 16 + ((lane >> 4) << 2) + i;
      outp[row * 64 + col] = (_Float16)acc[m][i];
    }
  }
}

// ---------------------------------------------------------------------------
// Combine 4 fp16 partials -> KVTx fp16 [64 bh][80 rows][64 cols]
// ---------------------------------------------------------------------------
__global__ __launch_bounds__(256)
void kv_combine(const _Float16* __restrict__ pKV, _Float16* __restrict__ KVTx) {
  int g = blockIdx.x * 256 + threadIdx.x;   // 0..327679
  int bh = g / 5120;
  int j  = g - bh * 5120;
  float s = 0.f;
#pragma unroll
  for (int ch = 0; ch < 4; ++ch)
    s += (float)pKV[((size_t)ch * 64 + bh) * 5120 + j];
  KVTx[(size_t)bh * 5120 + j] = (_Float16)s;
}

// ---------------------------------------------------------------------------
extern "C" void kernel_launch(void* const* d_in, const int* in_sizes, int n_in,
                              void* d_out, int out_size, void* d_ws, size_t ws_size,
                              hipStream_t stream) {
  const float* q  = (const float*)d_in[0];
  const float* k  = (const float*)d_in[1];
  const float* v  = (const float*)d_in[2];
  const float* wq = (const float*)d_in[3];
  const float* bq = (const float*)d_in[4];
  const float* wk = (const float*)d_in[5];
  const float* bk = (const float*)d_in[6];
  const float* wv = (const float*)d_in[7];
  const float* bv = (const float*)d_in[8];
  const float* wo = (const float*)d_in[9];
  const float* bo = (const float*)d_in[10];
  float* out = (float*)d_out;

  char* ws = (char*)d_ws;
  _Float16* Xq   = (_Float16*)(ws);                      // 0..32MB
  _Float16* KT   = (_Float16*)(ws + 33554432);           // 32..64MB
  _Float16* VT   = (_Float16*)(ws + 67108864);           // 64..96MB
  _Float16* pKV  = (_Float16*)(ws + 100663296);          // 2.62MB (over whk/whv later)
  _Float16* whk  = (_Float16*)(ws + 100663296);          // 2MB (dies after K-gemm)
  _Float16* whv  = (_Float16*)(ws + 102760448);          // 2MB (dies after V-gemm)
  _Float16* whq  = (_Float16*)(ws + 104857600);          // 2MB
  _Float16* who  = (_Float16*)(ws + 106954752);          // 2MB (lives to the end)
  _Float16* att  = KT;                                   // reuse KT after KV built
  // d_out (64MB) as scratch until the final GEMM:
  _Float16* Xk   = (_Float16*)d_out;                     // 0..32MB of d_out
  _Float16* Xv   = (_Float16*)((char*)d_out + 33554432); // 32..64MB of d_out
  _Float16* KVTx = (_Float16*)((char*)d_out + 33554432); // over dead Xv

  const int GBLK = (MROWS / 256) * (NDIM / 128);   // 512 blocks

  // weights: 1M elems each -> 128 blocks; inputs: 16.7M -> 2048 blocks
  cvt32<<<dim3(128, 4), 256, 0, stream>>>(wq, whq, wk, whk, wv, whv, wo, who);
  cvt32<<<dim3(2048, 3), 256, 0, stream>>>(k, Xk, v, Xv, q, Xq, nullptr, nullptr);

  // K/V projections (transposed per-head outputs)
  gemm_bk32<1, 1, 0, _Float16><<<GBLK, 512, 0, stream>>>(Xk, whk, bk, KT, nullptr);
  gemm_bk32<0, 1, 0, _Float16><<<GBLK, 512, 0, stream>>>(Xv, whv, bv, VT, nullptr);

  kv_mfma<<<dim3(64, 4), 256, 0, stream>>>(KT, VT, pKV);
  kv_combine<<<1280, 256, 0, stream>>>(pKV, KVTx);   // KVTx over dead Xv

  // Q projection + attention fused (BK32 + global-B-frag epilogue)
  gemm_bk32<1, 0, 1, _Float16><<<GBLK, 512, 0, stream>>>(Xq, whq, bq, att, KVTx);

  // output projection; overwrites all of d_out (Xk/KVTx dead)
  gemm_bk32<0, 0, 0, float><<<GBLK, 512, 0, stream>>>(att, who, bo, out, nullptr);
}